// Round 1
// baseline (326.306 us; speedup 1.0000x reference)
//
#include <hip/hip_runtime.h>
#include <stdint.h>

// Problem constants (compile-time; mem_size input ignored, == 128)
#define B_SZ 32
#define L_SZ 641
#define C_SZ 768
#define H_SZ 12
#define HD 64
#define MEMK 128
#define M_REAL (B_SZ * L_SZ)   // 20512
#define M_PAD 20608            // 161 * 128
#define N_QKV (3 * C_SZ)       // 2304
#define NQT 11                 // ceil(641/64)

typedef __attribute__((ext_vector_type(8))) short short8;
typedef __attribute__((ext_vector_type(4))) float f32x4;
typedef __attribute__((ext_vector_type(4))) unsigned short ushort4v;

__device__ inline unsigned short f2bf(float x) {
  union { float f; uint32_t u; } v; v.f = x;
  uint32_t r = v.u + 0x7fffu + ((v.u >> 16) & 1u);
  return (unsigned short)(r >> 16);
}

__device__ inline void gload_lds16(const void* g, void* l) {
  __builtin_amdgcn_global_load_lds(
      (const __attribute__((address_space(1))) uint32_t*)g,
      (__attribute__((address_space(3))) uint32_t*)l, 16, 0, 0);
}

// ---------------- conversion kernels ----------------
__global__ __launch_bounds__(256) void k_conv_x(const float* __restrict__ src,
                                                unsigned short* __restrict__ dst,
                                                int n4) {
  int i = blockIdx.x * 256 + threadIdx.x;
  if (i >= n4) return;
  float4 v = *(const float4*)(src + (size_t)i * 4);
  ushort4v o = { f2bf(v.x), f2bf(v.y), f2bf(v.z), f2bf(v.w) };
  *(ushort4v*)(dst + (size_t)i * 4) = o;
}

// dst[c][r] = bf16(src[r][c]); R, Ccol multiples of 32
__global__ __launch_bounds__(256) void k_transpose_bf16(const float* __restrict__ src,
                                                        unsigned short* __restrict__ dst,
                                                        int R, int Ccol) {
  __shared__ float tile[32][33];
  int c0 = blockIdx.x * 32, r0 = blockIdx.y * 32;
  int tx = threadIdx.x & 31, ty = threadIdx.x >> 5;
  for (int i = ty; i < 32; i += 8)
    tile[i][tx] = src[(size_t)(r0 + i) * Ccol + c0 + tx];
  __syncthreads();
  for (int i = ty; i < 32; i += 8)
    dst[(size_t)(c0 + i) * R + r0 + tx] = f2bf(tile[tx][i]);
}

// ---------------- GEMM: C[m][n] = sum_k A[m][k]*Bt[n][k] ----------------
// A: [Mpad][K] bf16, Bt: [N][K] bf16.  128x128 tile, BK=64, 4 waves.
template <int OUT_BF16>
__global__ __launch_bounds__(256) void k_gemm(const short* __restrict__ A,
                                              const short* __restrict__ Bt,
                                              void* __restrict__ Cp,
                                              int Mreal, int N, int K) {
  __shared__ short As[128 * 64];
  __shared__ short Bs[128 * 64];
  const int tiles_n = N >> 7;
  int tm = blockIdx.x / tiles_n, tn = blockIdx.x % tiles_n;
  int m0 = tm << 7, n0 = tn << 7;
  int lane = threadIdx.x & 63, wave = threadIdx.x >> 6;
  int wr = wave >> 1, wc = wave & 1;
  int l15 = lane & 15, g = lane >> 4;

  f32x4 acc[4][4];
  f32x4 z = {0.f, 0.f, 0.f, 0.f};
#pragma unroll
  for (int i = 0; i < 4; ++i)
#pragma unroll
    for (int j = 0; j < 4; ++j) acc[i][j] = z;

  int arow = lane >> 3;          // 0..7 rows within 8-row chunk
  int acol = (lane & 7) * 8;     // elem offset within 64

  for (int k0 = 0; k0 < K; k0 += 64) {
    __syncthreads();
#pragma unroll
    for (int cc = 0; cc < 4; ++cc) {
      int rb = (cc * 4 + wave) * 8;  // wave-uniform row base
      gload_lds16(A + (size_t)(m0 + rb + arow) * K + (k0 + acol),
                  (char*)As + rb * 128);
      gload_lds16(Bt + (size_t)(n0 + rb + arow) * K + (k0 + acol),
                  (char*)Bs + rb * 128);
    }
    __syncthreads();
#pragma unroll
    for (int ks = 0; ks < 2; ++ks) {
      short8 a[4], b[4];
#pragma unroll
      for (int mf = 0; mf < 4; ++mf)
        a[mf] = *(const short8*)&As[(wr * 64 + mf * 16 + l15) * 64 + ks * 32 + g * 8];
#pragma unroll
      for (int nf = 0; nf < 4; ++nf)
        b[nf] = *(const short8*)&Bs[(wc * 64 + nf * 16 + l15) * 64 + ks * 32 + g * 8];
#pragma unroll
      for (int mf = 0; mf < 4; ++mf)
#pragma unroll
        for (int nf = 0; nf < 4; ++nf)
          acc[mf][nf] = __builtin_amdgcn_mfma_f32_16x16x32_bf16(a[mf], b[nf], acc[mf][nf], 0, 0, 0);
    }
  }
  // epilogue: D row = g*4+reg, col = l15 (m89-verified layout)
#pragma unroll
  for (int mf = 0; mf < 4; ++mf) {
#pragma unroll
    for (int reg = 0; reg < 4; ++reg) {
      int m = m0 + wr * 64 + mf * 16 + g * 4 + reg;
      if (m >= Mreal) continue;
#pragma unroll
      for (int nf = 0; nf < 4; ++nf) {
        int n = n0 + wc * 64 + nf * 16 + l15;
        float v = acc[mf][nf][reg];
        if (OUT_BF16)
          ((unsigned short*)Cp)[(size_t)m * N + n] = f2bf(v);
        else
          ((float*)Cp)[(size_t)m * N + n] = v;
      }
    }
  }
}

// ---------------- fused masked attention ----------------
// grid: B*H*NQT blocks, 256 threads (4 waves x 16 q-rows)
__global__ __launch_bounds__(256) void k_attn(const short* __restrict__ qkv,  // [M_PAD][2304]
                                              short* __restrict__ y) {        // [M_PAD][768]
  __shared__ short Ks[64 * 72];       // K tile row-major [key][d], padded stride
  __shared__ short Vt[64 * 72];       // V^T tile [d][key], padded stride
  __shared__ short Ps[4][16 * 72];    // per-wave P [q][key], padded stride

  int x = blockIdx.x;
  int qt = x % NQT;
  int h = (x / NQT) % H_SZ;
  int b = x / (NQT * H_SZ);
  int q0 = qt * 64;
  int lane = threadIdx.x & 63, w = threadIdx.x >> 6;
  int l15 = lane & 15, g = lane >> 4;

  // Q fragments in registers (A-frag: row = l15, k = g*8+i, per 32-wide kstep)
  size_t qbase = (size_t)(b * L_SZ + q0 + w * 16 + l15) * N_QKV;
  short8 qa[2];
#pragma unroll
  for (int ks = 0; ks < 2; ++ks)
    qa[ks] = *(const short8*)&qkv[qbase + h * HD + ks * 32 + g * 8];

  f32x4 o[4];
  float m_run[4], l_run[4];
  f32x4 z = {0.f, 0.f, 0.f, 0.f};
#pragma unroll
  for (int df = 0; df < 4; ++df) o[df] = z;
#pragma unroll
  for (int r = 0; r < 4; ++r) { m_run[r] = -1e30f; l_run[r] = 0.f; }

  int q1 = q0 + 63; if (q1 > L_SZ - 1) q1 = L_SZ - 1;
  int col_max = (q0 <= MEMK && MEMK <= q1) ? (L_SZ - 1) : (q1 < MEMK ? MEMK : q1);

  for (int c0 = 0; c0 <= col_max; c0 += 64) {
    __syncthreads();
    // stage K rows [c0, c0+64): rows beyond L read in-bounds garbage (masked later)
#pragma unroll
    for (int it = 0; it < 2; ++it) {
      int idx = threadIdx.x + it * 256;
      int kk = idx >> 3, j = (idx & 7) * 8;
      short8 kv = *(const short8*)&qkv[(size_t)(b * L_SZ + c0 + kk) * N_QKV + C_SZ + h * HD + j];
      *(short8*)&Ks[kk * 72 + j] = kv;
    }
    // stage V transposed: per-lane scalar gathers, contiguous LDS writes
    {
      int d = threadIdx.x >> 2;
#pragma unroll
      for (int it = 0; it < 2; ++it) {
        int kk0 = ((threadIdx.x & 3) + it * 4) * 8;
        short8 vv;
#pragma unroll
        for (int i2 = 0; i2 < 8; ++i2)
          vv[i2] = qkv[(size_t)(b * L_SZ + c0 + kk0 + i2) * N_QKV + 2 * C_SZ + h * HD + d];
        *(short8*)&Vt[d * 72 + kk0] = vv;
      }
    }
    __syncthreads();

    // S = Q K^T  (D: row=q=g*4+reg, col=key=l15 within each 16-wide kf frag)
    f32x4 s[4];
#pragma unroll
    for (int kf = 0; kf < 4; ++kf) {
      f32x4 sa = z;
#pragma unroll
      for (int ks = 0; ks < 2; ++ks) {
        short8 kb = *(const short8*)&Ks[(kf * 16 + l15) * 72 + ks * 32 + g * 8];
        sa = __builtin_amdgcn_mfma_f32_16x16x32_bf16(qa[ks], kb, sa, 0, 0, 0);
      }
      s[kf] = sa;
    }

    // mask + scale:  valid = (i==MEM) || (i<MEM ? j<=MEM : j<=i), j<L
#pragma unroll
    for (int kf = 0; kf < 4; ++kf) {
      int j = c0 + kf * 16 + l15;
#pragma unroll
      for (int reg = 0; reg < 4; ++reg) {
        int i = q0 + w * 16 + g * 4 + reg;
        bool valid = (j < L_SZ) && ((i == MEMK) || (i < MEMK ? (j <= MEMK) : (j <= i)));
        s[kf][reg] = valid ? s[kf][reg] * 0.125f : -1e30f;
      }
    }

    // online softmax (stats per row; keys spread over 16-lane group)
    float corr[4];
#pragma unroll
    for (int reg = 0; reg < 4; ++reg) {
      float t = fmaxf(fmaxf(s[0][reg], s[1][reg]), fmaxf(s[2][reg], s[3][reg]));
      t = fmaxf(t, __shfl_xor(t, 1));
      t = fmaxf(t, __shfl_xor(t, 2));
      t = fmaxf(t, __shfl_xor(t, 4));
      t = fmaxf(t, __shfl_xor(t, 8));
      float mn = fmaxf(m_run[reg], t);
      corr[reg] = __expf(m_run[reg] - mn);
      m_run[reg] = mn;
    }
#pragma unroll
    for (int kf = 0; kf < 4; ++kf)
#pragma unroll
      for (int reg = 0; reg < 4; ++reg)
        s[kf][reg] = __expf(s[kf][reg] - m_run[reg]);
#pragma unroll
    for (int reg = 0; reg < 4; ++reg) {
      float ls = s[0][reg] + s[1][reg] + s[2][reg] + s[3][reg];
      ls += __shfl_xor(ls, 1);
      ls += __shfl_xor(ls, 2);
      ls += __shfl_xor(ls, 4);
      ls += __shfl_xor(ls, 8);
      l_run[reg] = l_run[reg] * corr[reg] + ls;
      o[0][reg] *= corr[reg];
      o[1][reg] *= corr[reg];
      o[2][reg] *= corr[reg];
      o[3][reg] *= corr[reg];
    }

    // P -> LDS (bf16), then PV
#pragma unroll
    for (int kf = 0; kf < 4; ++kf)
#pragma unroll
      for (int reg = 0; reg < 4; ++reg)
        Ps[w][(g * 4 + reg) * 72 + kf * 16 + l15] = (short)f2bf(s[kf][reg]);
    __syncthreads();  // safety: order P write -> P read (remove after A/B later)

    short8 pa[2];
#pragma unroll
    for (int ks = 0; ks < 2; ++ks)
      pa[ks] = *(const short8*)&Ps[w][l15 * 72 + ks * 32 + g * 8];
#pragma unroll
    for (int df = 0; df < 4; ++df) {
#pragma unroll
      for (int ks = 0; ks < 2; ++ks) {
        short8 vb = *(const short8*)&Vt[(df * 16 + l15) * 72 + ks * 32 + g * 8];
        o[df] = __builtin_amdgcn_mfma_f32_16x16x32_bf16(pa[ks], vb, o[df], 0, 0, 0);
      }
    }
  }

  // epilogue
#pragma unroll
  for (int reg = 0; reg < 4; ++reg) {
    int i = q0 + w * 16 + g * 4 + reg;
    if (i >= L_SZ) continue;
    float inv = 1.0f / l_run[reg];
#pragma unroll
    for (int df = 0; df < 4; ++df)
      y[(size_t)(b * L_SZ + i) * C_SZ + h * HD + df * 16 + l15] = (short)f2bf(o[df][reg] * inv);
  }
}

// ---------------- launch ----------------
extern "C" void kernel_launch(void* const* d_in, const int* in_sizes, int n_in,
                              void* d_out, int out_size, void* d_ws, size_t ws_size,
                              hipStream_t stream) {
  const float* x = (const float*)d_in[0];
  const float* Wa = (const float*)d_in[1];
  const float* Wp = (const float*)d_in[2];
  float* out = (float*)d_out;

  char* ws = (char*)d_ws;
  size_t off0 = 0;
  short* x_bf = (short*)(ws + off0);                       // [M_PAD][768], reused as y
  size_t off1 = off0 + (size_t)M_PAD * C_SZ * 2;
  short* Wa_t = (short*)(ws + off1);                       // [2304][768]
  size_t off2 = off1 + (size_t)N_QKV * C_SZ * 2;
  short* Wp_t = (short*)(ws + off2);                       // [768][768]
  size_t off3 = off2 + (size_t)C_SZ * C_SZ * 2;
  short* qkv = (short*)(ws + off3);                        // [M_PAD][2304]
  size_t need = off3 + (size_t)M_PAD * N_QKV * 2;
  if (ws_size < need) return;  // ~131.4 MB required

  int n4 = M_REAL * C_SZ / 4;
  k_conv_x<<<(n4 + 255) / 256, 256, 0, stream>>>(x, (unsigned short*)x_bf, n4);
  k_transpose_bf16<<<dim3(N_QKV / 32, C_SZ / 32), 256, 0, stream>>>(Wa, (unsigned short*)Wa_t, C_SZ, N_QKV);
  k_transpose_bf16<<<dim3(C_SZ / 32, C_SZ / 32), 256, 0, stream>>>(Wp, (unsigned short*)Wp_t, C_SZ, C_SZ);

  k_gemm<1><<<(M_PAD / 128) * (N_QKV / 128), 256, 0, stream>>>(x_bf, Wa_t, (void*)qkv, M_REAL, N_QKV, C_SZ);
  k_attn<<<B_SZ * H_SZ * NQT, 256, 0, stream>>>(qkv, x_bf /* y reuses x_bf */);
  k_gemm<0><<<(M_PAD / 128) * (C_SZ / 128), 256, 0, stream>>>(x_bf, Wp_t, (void*)out, M_REAL, C_SZ, C_SZ);
}